// Round 3
// baseline (451.210 us; speedup 1.0000x reference)
//
#include <hip/hip_runtime.h>
#include <hip/hip_bf16.h>
#include <math.h>

#define D_MODEL 1024
#define NH 16
#define HD 64
#define SEQ 2048
#define BATCH 2
#define NTOK (BATCH*SEQ)   // 4096

typedef short bf16x8 __attribute__((ext_vector_type(8)));
typedef float f32x4 __attribute__((ext_vector_type(4)));

#define MFMA(a,b,c) __builtin_amdgcn_mfma_f32_16x16x32_bf16(a,b,c,0,0,0)

union bfu { __hip_bfloat16 b; unsigned short u; };
__device__ __forceinline__ unsigned short f2b(float f){ bfu t; t.b = __float2bfloat16(f); return t.u; }
__device__ __forceinline__ float b2f(unsigned short u){ bfu t; t.u = u; return __bfloat162float(t.b); }

// ---- d_ws layout, in u16 (bf16-bit) units --------------------------------
// [0..1] int flag (0 = inputs already bf16, 1 = inputs are f32)
#define OFF_X   128L
#define OFF_WQ  (OFF_X  + 4194304L)   // x     : 4096*1024
#define OFF_BQ  (OFF_WQ + 3145728L)   // Wqkv  : 3072*1024
#define OFF_WP  (OFF_BQ + 3072L)      // bqkv
#define OFF_BP  (OFF_WP + 1048576L)   // Wproj : 1024*1024
#define OFF_QN  (OFF_BP + 1024L)      // bproj
#define OFF_KN  (OFF_QN + 64L)
#define OFF_Q   (OFF_KN + 64L)        // = 8392960, 16B aligned
#define OFF_K   (OFF_Q  + 4194304L)
#define OFF_V   (OFF_K  + 4194304L)
#define OFF_A   (OFF_V  + 4194304L)
#define CVT_N   8392832L              // total elements to canonicalize

// ---------------------------------------------------------------------------
// Kernel 0: dtype detector. bf16 N(0,1) data never has exponent field >=0x90
// (|x| >= 2^17); f32 bits read as u16 pairs have random exponents in the low
// half (~22% of all u16s >= 0x90). One block, deterministic.
// ---------------------------------------------------------------------------
__global__ __launch_bounds__(256) void detect_kernel(
    const unsigned short* __restrict__ xraw, int* __restrict__ flag)
{
    __shared__ int cnt;
    if (threadIdx.x == 0) cnt = 0;
    __syncthreads();
    int local = 0;
    for (int i = threadIdx.x; i < 65536; i += 256){
        int e = (xraw[i] >> 7) & 0xFF;
        if (e >= 0x90) local++;
    }
    atomicAdd(&cnt, local);
    __syncthreads();
    if (threadIdx.x == 0) *flag = (cnt > 256) ? 1 : 0;
}

// ---------------------------------------------------------------------------
// Kernel 0.5: canonicalize all inputs to bf16 bits in d_ws.
// ---------------------------------------------------------------------------
__global__ __launch_bounds__(256) void convert_kernel(
    const void* __restrict__ x,  const void* __restrict__ wq,
    const void* __restrict__ bq, const void* __restrict__ wp,
    const void* __restrict__ bp, const void* __restrict__ qn,
    const void* __restrict__ kn, unsigned short* __restrict__ ws,
    const int* __restrict__ flagp)
{
    const int flag = *flagp;
    long i = (long)blockIdx.x*blockDim.x + threadIdx.x;
    const long stride = (long)gridDim.x*blockDim.x;
    for (; i < CVT_N; i += stride){
        long j = i; const void* src; long off;
        if (j < 4194304L)                  { src = x;  off = OFF_X  + j; }
        else if ((j -= 4194304L) < 3145728L){ src = wq; off = OFF_WQ + j; }
        else if ((j -= 3145728L) < 3072L)   { src = bq; off = OFF_BQ + j; }
        else if ((j -= 3072L)    < 1048576L){ src = wp; off = OFF_WP + j; }
        else if ((j -= 1048576L) < 1024L)   { src = bp; off = OFF_BP + j; }
        else if ((j -= 1024L)    < 64L)     { src = qn; off = OFF_QN + j; }
        else      { j -= 64L;                 src = kn; off = OFF_KN + j; }
        ws[off] = flag ? f2b(((const float*)src)[j])
                       : ((const unsigned short*)src)[j];
    }
}

// ---------------------------------------------------------------------------
// Kernel 1: qkv = x @ Wqkv^T + bqkv, fused per-head RMS norm on q,k.
// A-frag: x[m0+(lane&15)][k0+quad*8+j]; B-frag: Wqkv[n0+(lane&15)][k0+quad*8+j]
// C/D: col = lane&15, row = quad*4+reg  [verified m89/m91]
// ---------------------------------------------------------------------------
__global__ __launch_bounds__(256) void qkv_kernel(
    const unsigned short* __restrict__ x,
    const unsigned short* __restrict__ Wqkv,
    const unsigned short* __restrict__ bqkv,
    const unsigned short* __restrict__ qn_w,
    const unsigned short* __restrict__ kn_w,
    unsigned short* __restrict__ qbuf,
    unsigned short* __restrict__ kbuf,
    unsigned short* __restrict__ vbuf)
{
    const int tid  = threadIdx.x;
    const int w    = tid >> 6;
    const int lane = tid & 63;
    const int quad = lane >> 4;
    const int c    = lane & 15;
    const int m0 = blockIdx.y*128 + (w>>1)*64;
    const int n0 = blockIdx.x*128 + (w&1)*64;

    f32x4 acc[4][4];
    for (int mi=0;mi<4;mi++) for (int ni=0;ni<4;ni++) acc[mi][ni] = {0.f,0.f,0.f,0.f};

    const unsigned short* xa = x    + (long)(m0 + c)*D_MODEL + quad*8;
    const unsigned short* wb = Wqkv + (long)(n0 + c)*D_MODEL + quad*8;

    for (int k0=0;k0<D_MODEL;k0+=32){
        bf16x8 a[4], b[4];
        for (int mi=0;mi<4;mi++) a[mi] = *(const bf16x8*)(xa + mi*16*D_MODEL + k0);
        for (int ni=0;ni<4;ni++) b[ni] = *(const bf16x8*)(wb + ni*16*D_MODEL + k0);
        for (int mi=0;mi<4;mi++)
            for (int ni=0;ni<4;ni++)
                acc[mi][ni] = MFMA(a[mi], b[ni], acc[mi][ni]);
    }

    const int region = n0 >> 10;          // 0=q, 1=k, 2=v
    const int h      = (n0 & 1023) >> 6;  // head index
    float bias[4], wn[4];
    for (int ni=0;ni<4;ni++){
        bias[ni] = b2f(bqkv[n0 + ni*16 + c]);
        wn[ni]   = 1.0f;
    }
    if (region==0) for (int ni=0;ni<4;ni++) wn[ni] = b2f(qn_w[ni*16+c]);
    if (region==1) for (int ni=0;ni<4;ni++) wn[ni] = b2f(kn_w[ni*16+c]);
    unsigned short* dst = (region==0) ? qbuf : (region==1) ? kbuf : vbuf;

    for (int mi=0;mi<4;mi++){
        for (int ni=0;ni<4;ni++)
            for (int r=0;r<4;r++) acc[mi][ni][r] += bias[ni];

        float scale_r[4];
        if (region < 2){
            for (int r=0;r<4;r++){
                float ss = 0.f;
                for (int ni=0;ni<4;ni++){ float v2 = acc[mi][ni][r]; ss += v2*v2; }
                ss += __shfl_xor(ss, 1, 64);
                ss += __shfl_xor(ss, 2, 64);
                ss += __shfl_xor(ss, 4, 64);
                ss += __shfl_xor(ss, 8, 64);
                scale_r[r] = rsqrtf(ss*(1.0f/64.0f) + 1e-6f);
            }
        } else {
            for (int r=0;r<4;r++) scale_r[r] = 1.0f;
        }

        for (int r=0;r<4;r++){
            int m = m0 + mi*16 + quad*4 + r;       // global token
            int bidx = m >> 11, s = m & 2047;
            long base = ((long)(bidx*NH + h)*SEQ + s)*HD;
            for (int ni=0;ni<4;ni++)
                dst[base + ni*16 + c] = f2b(acc[mi][ni][r] * scale_r[r] * wn[ni]);
        }
    }
}

// ---------------------------------------------------------------------------
// Kernel 2: flash attention (online softmax). Block = 4 waves = one (b,h) x
// 64 q rows. No inf anywhere (init -1e30f). Barriers around every LDS phase.
// ---------------------------------------------------------------------------
__global__ __launch_bounds__(256) void attn_kernel(
    const unsigned short* __restrict__ qbuf,
    const unsigned short* __restrict__ kbuf,
    const unsigned short* __restrict__ vbuf,
    unsigned short* __restrict__ abuf)
{
    const int tid  = threadIdx.x;
    const int w    = tid >> 6;
    const int lane = tid & 63;
    const int quad = lane >> 4;
    const int c    = lane & 15;
    const int bh = blockIdx.y;     // 0..31
    const int qt = blockIdx.x;     // 0..31
    const unsigned short* qb = qbuf + (long)bh*SEQ*HD;
    const unsigned short* kb = kbuf + (long)bh*SEQ*HD;
    const unsigned short* vb = vbuf + (long)bh*SEQ*HD;
    const int qbase = qt*64 + w*16;

    __shared__ __align__(16) short VT[HD][72];     // V transposed (dim-major)
    __shared__ __align__(16) short P[4][16][72];   // per-wave P tile

    bf16x8 aq[2];
    aq[0] = *(const bf16x8*)(qb + (long)(qbase + c)*HD + quad*8);
    aq[1] = *(const bf16x8*)(qb + (long)(qbase + c)*HD + 32 + quad*8);

    f32x4 o[4];
    for (int nt=0;nt<4;nt++) o[nt] = {0.f,0.f,0.f,0.f};
    float m_run[4], l_run[4];
    for (int r=0;r<4;r++){ m_run[r] = -1e30f; l_run[r] = 0.f; }

    for (int kt=0; kt<SEQ/64; kt++){
        const int key0 = kt*64;
        __syncthreads();                       // VT/P safe to overwrite
        for (int it=0; it<2; it++){
            int idx = tid + it*256;
            int key = idx >> 3;
            int dg  = (idx & 7)*8;
            bf16x8 vv = *(const bf16x8*)(vb + (long)(key0+key)*HD + dg);
            const short* ve = (const short*)&vv;
            for (int j=0;j<8;j++) VT[dg+j][key] = ve[j];
        }
        __syncthreads();                       // VT ready

        // S = Q K^T * scale
        f32x4 sf[4];
        for (int nt=0;nt<4;nt++){
            const unsigned short* kp = kb + (long)(key0 + nt*16 + c)*HD + quad*8;
            bf16x8 b0 = *(const bf16x8*)(kp);
            bf16x8 b1 = *(const bf16x8*)(kp + 32);
            f32x4 z = {0.f,0.f,0.f,0.f};
            z = MFMA(aq[0], b0, z);
            z = MFMA(aq[1], b1, z);
            for (int r=0;r<4;r++) sf[nt][r] = z[r]*0.125f;   // 1/sqrt(64)
        }

        // online softmax: row = quad*4+r, cols across {nt, c}
        float alpha[4];
        for (int r=0;r<4;r++){
            float mt = fmaxf(fmaxf(sf[0][r],sf[1][r]), fmaxf(sf[2][r],sf[3][r]));
            mt = fmaxf(mt, __shfl_xor(mt,1,64));
            mt = fmaxf(mt, __shfl_xor(mt,2,64));
            mt = fmaxf(mt, __shfl_xor(mt,4,64));
            mt = fmaxf(mt, __shfl_xor(mt,8,64));
            float mnew = fmaxf(m_run[r], mt);
            alpha[r] = __expf(m_run[r]-mnew);
            m_run[r] = mnew;
        }
        float rs[4] = {0.f,0.f,0.f,0.f};
        for (int nt=0;nt<4;nt++)
            for (int r=0;r<4;r++){
                float p = __expf(sf[nt][r]-m_run[r]);
                sf[nt][r] = p; rs[r] += p;
            }
        for (int r=0;r<4;r++){
            rs[r] += __shfl_xor(rs[r],1,64);
            rs[r] += __shfl_xor(rs[r],2,64);
            rs[r] += __shfl_xor(rs[r],4,64);
            rs[r] += __shfl_xor(rs[r],8,64);
            l_run[r] = l_run[r]*alpha[r] + rs[r];
            for (int nt=0;nt<4;nt++) o[nt][r] *= alpha[r];
        }

        // P (C-layout) -> LDS, then barrier before reading as A-frags
        for (int nt=0;nt<4;nt++)
            for (int r=0;r<4;r++)
                P[w][quad*4+r][nt*16+c] = (short)f2b(sf[nt][r]);
        __syncthreads();                       // P (and VT) ordered/visible

        // O += P V
        for (int ks=0;ks<2;ks++){
            bf16x8 ap = *(const bf16x8*)(&P[w][c][ks*32 + quad*8]);
            for (int nt=0;nt<4;nt++){
                bf16x8 bv = *(const bf16x8*)(&VT[nt*16+c][ks*32 + quad*8]);
                o[nt] = MFMA(ap, bv, o[nt]);
            }
        }
    }

    // epilogue: O/l, write [B,S,H,HD] (= token-major D)
    const int b = bh >> 4, h = bh & 15;
    for (int r=0;r<4;r++){
        int s = qbase + quad*4 + r;
        long base = ((long)(b*SEQ + s)*NH + h)*HD;
        float inv_l = 1.0f / l_run[r];
        for (int nt=0;nt<4;nt++)
            abuf[base + nt*16 + c] = f2b(o[nt][r]*inv_l);
    }
}

// ---------------------------------------------------------------------------
// Kernel 3: out = attn @ Wproj^T + bproj; store dtype per flag.
// ---------------------------------------------------------------------------
__global__ __launch_bounds__(256) void proj_kernel(
    const unsigned short* __restrict__ abuf,
    const unsigned short* __restrict__ Wp,
    const unsigned short* __restrict__ bp,
    void* __restrict__ outv,
    const int* __restrict__ flagp)
{
    const int tid  = threadIdx.x;
    const int w    = tid >> 6;
    const int lane = tid & 63;
    const int quad = lane >> 4;
    const int c    = lane & 15;
    const int m0 = blockIdx.y*128 + (w>>1)*64;
    const int n0 = blockIdx.x*128 + (w&1)*64;
    const int flag = *flagp;

    f32x4 acc[4][4];
    for (int mi=0;mi<4;mi++) for (int ni=0;ni<4;ni++) acc[mi][ni] = {0.f,0.f,0.f,0.f};

    const unsigned short* xa = abuf + (long)(m0 + c)*D_MODEL + quad*8;
    const unsigned short* wb = Wp   + (long)(n0 + c)*D_MODEL + quad*8;

    for (int k0=0;k0<D_MODEL;k0+=32){
        bf16x8 a[4], b[4];
        for (int mi=0;mi<4;mi++) a[mi] = *(const bf16x8*)(xa + mi*16*D_MODEL + k0);
        for (int ni=0;ni<4;ni++) b[ni] = *(const bf16x8*)(wb + ni*16*D_MODEL + k0);
        for (int mi=0;mi<4;mi++)
            for (int ni=0;ni<4;ni++)
                acc[mi][ni] = MFMA(a[mi], b[ni], acc[mi][ni]);
    }

    float bias[4];
    for (int ni=0;ni<4;ni++) bias[ni] = b2f(bp[n0 + ni*16 + c]);

    for (int mi=0;mi<4;mi++)
        for (int r=0;r<4;r++){
            long m = m0 + mi*16 + quad*4 + r;
            for (int ni=0;ni<4;ni++){
                float val = acc[mi][ni][r] + bias[ni];
                long idx = m*D_MODEL + n0 + ni*16 + c;
                if (flag) ((float*)outv)[idx] = val;
                else      ((unsigned short*)outv)[idx] = f2b(val);
            }
        }
}

extern "C" void kernel_launch(void* const* d_in, const int* in_sizes, int n_in,
                              void* d_out, int out_size, void* d_ws, size_t ws_size,
                              hipStream_t stream)
{
    unsigned short* ws = (unsigned short*)d_ws;
    int* flag = (int*)d_ws;

    hipLaunchKernelGGL(detect_kernel, dim3(1), dim3(256), 0, stream,
                       (const unsigned short*)d_in[0], flag);
    hipLaunchKernelGGL(convert_kernel, dim3(8192), dim3(256), 0, stream,
                       d_in[0], d_in[1], d_in[2], d_in[3], d_in[4], d_in[5], d_in[6],
                       ws, flag);
    hipLaunchKernelGGL(qkv_kernel,  dim3(24,32), dim3(256), 0, stream,
                       ws+OFF_X, ws+OFF_WQ, ws+OFF_BQ, ws+OFF_QN, ws+OFF_KN,
                       ws+OFF_Q, ws+OFF_K, ws+OFF_V);
    hipLaunchKernelGGL(attn_kernel, dim3(32,32), dim3(256), 0, stream,
                       ws+OFF_Q, ws+OFF_K, ws+OFF_V, ws+OFF_A);
    hipLaunchKernelGGL(proj_kernel, dim3(8,32),  dim3(256), 0, stream,
                       ws+OFF_A, ws+OFF_WP, ws+OFF_BP, d_out, flag);
}

// Round 4
// 336.273 us; speedup vs baseline: 1.3418x; 1.3418x over previous
//
#include <hip/hip_runtime.h>
#include <hip/hip_bf16.h>
#include <math.h>

#define D_MODEL 1024
#define NH 16
#define HD 64
#define SEQ 2048
#define BATCH 2
#define NTOK (BATCH*SEQ)   // 4096

typedef short bf16x8 __attribute__((ext_vector_type(8)));
typedef float f32x4 __attribute__((ext_vector_type(4)));
typedef unsigned short us4 __attribute__((ext_vector_type(4)));

#define MFMA(a,b,c) __builtin_amdgcn_mfma_f32_16x16x32_bf16(a,b,c,0,0,0)

union bfu { __hip_bfloat16 b; unsigned short u; };
__device__ __forceinline__ unsigned short f2b(float f){ bfu t; t.b = __float2bfloat16(f); return t.u; }
__device__ __forceinline__ float b2f(unsigned short u){ bfu t; t.u = u; return __bfloat162float(t.b); }

// async global->LDS, 16B per lane. LDS dest must equal wave-uniform base + lane*16.
__device__ __forceinline__ void g2l16(const unsigned short* g, unsigned short* l){
    __builtin_amdgcn_global_load_lds(
        (const __attribute__((address_space(1))) unsigned int*)g,
        (__attribute__((address_space(3))) unsigned int*)l, 16, 0, 0);
}

// ---- d_ws layout, in u16 units --------------------------------------------
#define OFF_X   128L
#define OFF_WQ  (OFF_X  + 4194304L)
#define OFF_BQ  (OFF_WQ + 3145728L)
#define OFF_WP  (OFF_BQ + 3072L)
#define OFF_BP  (OFF_WP + 1048576L)
#define OFF_QN  (OFF_BP + 1024L)
#define OFF_KN  (OFF_QN + 64L)
#define OFF_Q   (OFF_KN + 64L)
#define OFF_K   (OFF_Q  + 4194304L)
#define OFF_V   (OFF_K  + 4194304L)
#define OFF_A   (OFF_V  + 4194304L)

// ---------------------------------------------------------------------------
// dtype detector (unchanged; f32-as-u16 has ~22% exponents >= 0x90)
// ---------------------------------------------------------------------------
__global__ __launch_bounds__(256) void detect_kernel(
    const unsigned short* __restrict__ xraw, int* __restrict__ flag)
{
    __shared__ int cnt;
    if (threadIdx.x == 0) cnt = 0;
    __syncthreads();
    int local = 0;
    for (int i = threadIdx.x; i < 65536; i += 256){
        int e = (xraw[i] >> 7) & 0xFF;
        if (e >= 0x90) local++;
    }
    atomicAdd(&cnt, local);
    __syncthreads();
    if (threadIdx.x == 0) *flag = (cnt > 256) ? 1 : 0;
}

// ---------------------------------------------------------------------------
// canonicalize inputs to bf16, vectorized 4-wide (all segment sizes % 4 == 0)
// ---------------------------------------------------------------------------
__global__ __launch_bounds__(256) void convert_kernel(
    const void* __restrict__ x,  const void* __restrict__ wq,
    const void* __restrict__ bq, const void* __restrict__ wp,
    const void* __restrict__ bp, const void* __restrict__ qn,
    const void* __restrict__ kn, unsigned short* __restrict__ ws,
    const int* __restrict__ flagp)
{
    const int flag = *flagp;
    long i = (long)blockIdx.x*blockDim.x + threadIdx.x;   // 4-elem chunk id
    const long stride = (long)gridDim.x*blockDim.x;
    const long NCH = 2098208L;                            // 8392832/4
    for (; i < NCH; i += stride){
        long j = i; const void* src; long off;
        if (j < 1048576L)                  { src = x;  off = OFF_X;  }
        else if ((j -= 1048576L) < 786432L){ src = wq; off = OFF_WQ; }
        else if ((j -= 786432L)  < 768L)   { src = bq; off = OFF_BQ; }
        else if ((j -= 768L)     < 262144L){ src = wp; off = OFF_WP; }
        else if ((j -= 262144L)  < 256L)   { src = bp; off = OFF_BP; }
        else if ((j -= 256L)     < 16L)    { src = qn; off = OFF_QN; }
        else      { j -= 16L;                src = kn; off = OFF_KN; }
        us4 o;
        if (flag){
            float4 v = ((const float4*)src)[j];
            o.x = f2b(v.x); o.y = f2b(v.y); o.z = f2b(v.z); o.w = f2b(v.w);
        } else {
            o = ((const us4*)src)[j];
        }
        *(us4*)(ws + off + j*4) = o;
    }
}

// ---------------------------------------------------------------------------
// Kernel 1: qkv = x @ Wqkv^T + bqkv, fused per-head RMS norm on q,k.
// m97 structure: 128x128 tile, BK=32, global_load_lds(16B) staging, 2-barrier.
// ---------------------------------------------------------------------------
__global__ __launch_bounds__(256) void qkv_kernel(
    const unsigned short* __restrict__ x,
    const unsigned short* __restrict__ Wqkv,
    const unsigned short* __restrict__ bqkv,
    const unsigned short* __restrict__ qn_w,
    const unsigned short* __restrict__ kn_w,
    unsigned short* __restrict__ qbuf,
    unsigned short* __restrict__ kbuf,
    unsigned short* __restrict__ vbuf)
{
    __shared__ __align__(16) unsigned short tA[128*32];
    __shared__ __align__(16) unsigned short tB[128*32];
    const int tid  = threadIdx.x;
    const int w    = tid >> 6, lane = tid & 63, quad = lane >> 4, c = lane & 15;
    const int m0 = blockIdx.y*128, n0 = blockIdx.x*128;
    const int am = (w>>1)*64, bn = (w&1)*64;

    f32x4 acc[4][4];
    for (int mi=0;mi<4;mi++) for (int ni=0;ni<4;ni++) acc[mi][ni] = {0.f,0.f,0.f,0.f};

    const int i0 = tid, i1 = tid + 256;
    const long ga0 = (long)(m0 + (i0>>2))*D_MODEL + (i0&3)*8;
    const long ga1 = (long)(m0 + (i1>>2))*D_MODEL + (i1&3)*8;
    const long gb0 = (long)(n0 + (i0>>2))*D_MODEL + (i0&3)*8;
    const long gb1 = (long)(n0 + (i1>>2))*D_MODEL + (i1&3)*8;

    for (int k0=0;k0<D_MODEL;k0+=32){
        g2l16(x    + ga0 + k0, tA + i0*8);
        g2l16(x    + ga1 + k0, tA + i1*8);
        g2l16(Wqkv + gb0 + k0, tB + i0*8);
        g2l16(Wqkv + gb1 + k0, tB + i1*8);
        __syncthreads();
        bf16x8 a[4], b[4];
        for (int mi=0;mi<4;mi++) a[mi] = *(const bf16x8*)(tA + (am + mi*16 + c)*32 + quad*8);
        for (int ni=0;ni<4;ni++) b[ni] = *(const bf16x8*)(tB + (bn + ni*16 + c)*32 + quad*8);
        for (int mi=0;mi<4;mi++)
            for (int ni=0;ni<4;ni++)
                acc[mi][ni] = MFMA(a[mi], b[ni], acc[mi][ni]);
        __syncthreads();
    }

    const int nw = n0 + bn, mw = m0 + am;
    const int region = nw >> 10;          // 0=q, 1=k, 2=v
    const int h      = (nw & 1023) >> 6;
    float bias[4], wn[4];
    for (int ni=0;ni<4;ni++){
        bias[ni] = b2f(bqkv[nw + ni*16 + c]);
        wn[ni]   = 1.0f;
    }
    if (region==0) for (int ni=0;ni<4;ni++) wn[ni] = b2f(qn_w[ni*16+c]);
    if (region==1) for (int ni=0;ni<4;ni++) wn[ni] = b2f(kn_w[ni*16+c]);
    unsigned short* dst = (region==0) ? qbuf : (region==1) ? kbuf : vbuf;

    for (int mi=0;mi<4;mi++){
        for (int ni=0;ni<4;ni++)
            for (int r=0;r<4;r++) acc[mi][ni][r] += bias[ni];

        float scale_r[4];
        if (region < 2){
            for (int r=0;r<4;r++){
                float ss = 0.f;
                for (int ni=0;ni<4;ni++){ float v2 = acc[mi][ni][r]; ss += v2*v2; }
                ss += __shfl_xor(ss, 1, 64);
                ss += __shfl_xor(ss, 2, 64);
                ss += __shfl_xor(ss, 4, 64);
                ss += __shfl_xor(ss, 8, 64);
                scale_r[r] = rsqrtf(ss*(1.0f/64.0f) + 1e-6f);
            }
        } else {
            for (int r=0;r<4;r++) scale_r[r] = 1.0f;
        }

        for (int r=0;r<4;r++){
            int m = mw + mi*16 + quad*4 + r;
            int bidx = m >> 11, s = m & 2047;
            long base = ((long)(bidx*NH + h)*SEQ + s)*HD;
            for (int ni=0;ni<4;ni++)
                dst[base + ni*16 + c] = f2b(acc[mi][ni][r] * scale_r[r] * wn[ni]);
        }
    }
}

// ---------------------------------------------------------------------------
// Kernel 2: attention, fixed-max softmax (|s| <= 8.2 by Cauchy-Schwarz since
// RMS-normed rows have L2 norm 8; M=12). Row-sum via ones-column in V (5th
// n-tile of PV). Block = 4 waves x 32 q rows = 128 q rows, one (b,h).
// V^T double-buffered in LDS (1 barrier/tile), XOR bank swizzles, K from L1.
// ---------------------------------------------------------------------------
__global__ __launch_bounds__(256) void attn_kernel(
    const unsigned short* __restrict__ qbuf,
    const unsigned short* __restrict__ kbuf,
    const unsigned short* __restrict__ vbuf,
    unsigned short* __restrict__ abuf)
{
    const int tid = threadIdx.x, w = tid>>6, lane = tid&63, quad = lane>>4, c = lane&15;
    const int bh = blockIdx.y, qt = blockIdx.x;
    const unsigned short* qb = qbuf + (long)bh*SEQ*HD;
    const unsigned short* kb = kbuf + (long)bh*SEQ*HD;
    const unsigned short* vb = vbuf + (long)bh*SEQ*HD;
    const int qbase = qt*128 + w*32;

    __shared__ __align__(16) unsigned short VT[2][80][72];  // [buf][d][key^ (d&0x38)]
    __shared__ __align__(16) unsigned short P[4][32][72];   // [wave][row][key ^ ((row&0xC)<<1)]

    // rows 64..79 of both VT buffers: zeros, then ones at d=64 (the sum column)
    for (int i = tid; i < 2*16*72; i += 256){
        int bi = i / (16*72), rr = (i/72) & 15, cc = i % 72;
        VT[bi][64+rr][cc] = 0;
    }
    __syncthreads();
    if (tid < 128) VT[tid>>6][64][tid&63] = 0x3F80;   // bf16 1.0
    __syncthreads();

    bf16x8 aq[2][2];
    for (int mi=0;mi<2;mi++)
        for (int ks=0;ks<2;ks++)
            aq[mi][ks] = *(const bf16x8*)(qb + (long)(qbase + mi*16 + c)*HD + ks*32 + quad*8);

    f32x4 o[2][5];
    for (int mi=0;mi<2;mi++) for (int nt=0;nt<5;nt++) o[mi][nt] = {0.f,0.f,0.f,0.f};

    for (int kt=0; kt<SEQ/64; kt++){
        const int key0 = kt*64;
        unsigned short (*vt)[72] = VT[kt&1];

        // stage V^T (transposed, bank-swizzled: conflict-free writes)
        for (int it=0; it<2; it++){
            int idx = tid + it*256;
            int key = idx >> 3, dg = (idx & 7)*8;
            bf16x8 vv = *(const bf16x8*)(vb + (long)(key0+key)*HD + dg);
            const unsigned short* ve = (const unsigned short*)&vv;
            int col = key ^ dg;                       // dg == (d & 0x38) for d in [dg,dg+8)
            for (int j=0;j<8;j++) vt[dg+j][col] = ve[j];
        }
        __syncthreads();   // publishes vt; prev buffer's readers already passed last barrier

        // S = Q K^T (K frags direct from global; 8KB tile is L1-resident)
        f32x4 z[2][4];
        for (int nt=0;nt<4;nt++){
            const unsigned short* kp = kb + (long)(key0 + nt*16 + c)*HD + quad*8;
            bf16x8 b0 = *(const bf16x8*)(kp);
            bf16x8 b1 = *(const bf16x8*)(kp + 32);
            for (int mi=0;mi<2;mi++){
                f32x4 t = {0.f,0.f,0.f,0.f};
                t = MFMA(aq[mi][0], b0, t);
                t = MFMA(aq[mi][1], b1, t);
                z[mi][nt] = t;
            }
        }

        // p = exp(s - 12), s = z/8  ->  exp2(z*0.125*log2e - 12*log2e)
        for (int mi=0;mi<2;mi++)
            for (int nt=0;nt<4;nt++)
                for (int r=0;r<4;r++){
                    float p = exp2f(z[mi][nt][r]*0.18033688f - 17.312340f);
                    P[w][mi*16 + quad*4 + r][(nt*16 + c) ^ (quad<<3)] = f2b(p);
                }

        // O += P V (wave-private P round-trip; in-wave DS ordering suffices)
        for (int ks=0;ks<2;ks++){
            bf16x8 bv[5];
            for (int nt=0;nt<5;nt++){
                int row = nt*16 + c;
                bv[nt] = *(const bf16x8*)(&vt[row][(ks*32 + quad*8) ^ (row & 0x38)]);
            }
            for (int mi=0;mi<2;mi++){
                bf16x8 ap = *(const bf16x8*)(&P[w][mi*16 + c][(ks*32 + quad*8) ^ ((c & 0x0C)<<1)]);
                for (int nt=0;nt<5;nt++)
                    o[mi][nt] = MFMA(ap, bv[nt], o[mi][nt]);
            }
        }
    }

    // epilogue: l lives in o[mi][4][r] at lane c=0 of each quad
    const int b = bh >> 4, h = bh & 15;
    for (int mi=0;mi<2;mi++)
        for (int r=0;r<4;r++){
            float l = __shfl(o[mi][4][r], (lane & 0x30), 64);
            float inv = 1.0f / l;
            int s = qbase + mi*16 + quad*4 + r;
            long base = ((long)(b*SEQ + s)*NH + h)*HD;
            for (int nt=0;nt<4;nt++)
                abuf[base + nt*16 + c] = f2b(o[mi][nt][r]*inv);
        }
}

// ---------------------------------------------------------------------------
// Kernel 3: out = attn @ Wproj^T + bproj (m97 structure), output dtype by flag
// ---------------------------------------------------------------------------
__global__ __launch_bounds__(256) void proj_kernel(
    const unsigned short* __restrict__ abuf,
    const unsigned short* __restrict__ Wp,
    const unsigned short* __restrict__ bp,
    void* __restrict__ outv,
    const int* __restrict__ flagp)
{
    __shared__ __align__(16) unsigned short tA[128*32];
    __shared__ __align__(16) unsigned short tB[128*32];
    const int tid  = threadIdx.x;
    const int w    = tid >> 6, lane = tid & 63, quad = lane >> 4, c = lane & 15;
    const int m0 = blockIdx.y*128, n0 = blockIdx.x*128;
    const int am = (w>>1)*64, bn = (w&1)*64;
    const int flag = *flagp;

    f32x4 acc[4][4];
    for (int mi=0;mi<4;mi++) for (int ni=0;ni<4;ni++) acc[mi][ni] = {0.f,0.f,0.f,0.f};

    const int i0 = tid, i1 = tid + 256;
    const long ga0 = (long)(m0 + (i0>>2))*D_MODEL + (i0&3)*8;
    const long ga1 = (long)(m0 + (i1>>2))*D_MODEL + (i1&3)*8;
    const long gb0 = (long)(n0 + (i0>>2))*D_MODEL + (i0&3)*8;
    const long gb1 = (long)(n0 + (i1>>2))*D_MODEL + (i1&3)*8;

    for (int k0=0;k0<D_MODEL;k0+=32){
        g2l16(abuf + ga0 + k0, tA + i0*8);
        g2l16(abuf + ga1 + k0, tA + i1*8);
        g2l16(Wp   + gb0 + k0, tB + i0*8);
        g2l16(Wp   + gb1 + k0, tB + i1*8);
        __syncthreads();
        bf16x8 a[4], b[4];
        for (int mi=0;mi<4;mi++) a[mi] = *(const bf16x8*)(tA + (am + mi*16 + c)*32 + quad*8);
        for (int ni=0;ni<4;ni++) b[ni] = *(const bf16x8*)(tB + (bn + ni*16 + c)*32 + quad*8);
        for (int mi=0;mi<4;mi++)
            for (int ni=0;ni<4;ni++)
                acc[mi][ni] = MFMA(a[mi], b[ni], acc[mi][ni]);
        __syncthreads();
    }

    float bias[4];
    for (int ni=0;ni<4;ni++) bias[ni] = b2f(bp[n0 + bn + ni*16 + c]);

    for (int mi=0;mi<4;mi++)
        for (int r=0;r<4;r++){
            long m = m0 + am + mi*16 + quad*4 + r;
            for (int ni=0;ni<4;ni++){
                float val = acc[mi][ni][r] + bias[ni];
                long idx = m*D_MODEL + n0 + bn + ni*16 + c;
                if (flag) ((float*)outv)[idx] = val;
                else      ((unsigned short*)outv)[idx] = f2b(val);
            }
        }
}

extern "C" void kernel_launch(void* const* d_in, const int* in_sizes, int n_in,
                              void* d_out, int out_size, void* d_ws, size_t ws_size,
                              hipStream_t stream)
{
    unsigned short* ws = (unsigned short*)d_ws;
    int* flag = (int*)d_ws;

    hipLaunchKernelGGL(detect_kernel, dim3(1), dim3(256), 0, stream,
                       (const unsigned short*)d_in[0], flag);
    hipLaunchKernelGGL(convert_kernel, dim3(2048), dim3(256), 0, stream,
                       d_in[0], d_in[1], d_in[2], d_in[3], d_in[4], d_in[5], d_in[6],
                       ws, flag);
    hipLaunchKernelGGL(qkv_kernel,  dim3(24,32), dim3(256), 0, stream,
                       ws+OFF_X, ws+OFF_WQ, ws+OFF_BQ, ws+OFF_QN, ws+OFF_KN,
                       ws+OFF_Q, ws+OFF_K, ws+OFF_V);
    hipLaunchKernelGGL(attn_kernel, dim3(16,32), dim3(256), 0, stream,
                       ws+OFF_Q, ws+OFF_K, ws+OFF_V, ws+OFF_A);
    hipLaunchKernelGGL(proj_kernel, dim3(8,32),  dim3(256), 0, stream,
                       ws+OFF_A, ws+OFF_WP, ws+OFF_BP, d_out, flag);
}

// Round 5
// 247.968 us; speedup vs baseline: 1.8196x; 1.3561x over previous
//
#include <hip/hip_runtime.h>
#include <hip/hip_bf16.h>
#include <math.h>

#define D_MODEL 1024
#define NH 16
#define HD 64
#define SEQ 2048
#define BATCH 2
#define NTOK (BATCH*SEQ)   // 4096

typedef short bf16x8 __attribute__((ext_vector_type(8)));
typedef short s4 __attribute__((ext_vector_type(4)));
typedef float f32x4 __attribute__((ext_vector_type(4)));
typedef unsigned short us4 __attribute__((ext_vector_type(4)));

#define MFMA(a,b,c) __builtin_amdgcn_mfma_f32_16x16x32_bf16(a,b,c,0,0,0)

union bfu { __hip_bfloat16 b; unsigned short u; };
__device__ __forceinline__ unsigned short f2b(float f){ bfu t; t.b = __float2bfloat16(f); return t.u; }
__device__ __forceinline__ float b2f(unsigned short u){ bfu t; t.u = u; return __bfloat162float(t.b); }

// async global->LDS, 16B per lane. LDS dest must equal wave-uniform base + lane*16.
__device__ __forceinline__ void g2l16(const unsigned short* g, unsigned short* l){
    __builtin_amdgcn_global_load_lds(
        (const __attribute__((address_space(1))) unsigned int*)g,
        (__attribute__((address_space(3))) unsigned int*)l, 16, 0, 0);
}

// ---- d_ws layout, in u16 units --------------------------------------------
#define OFF_X   128L
#define OFF_WQ  (OFF_X  + 4194304L)
#define OFF_BQ  (OFF_WQ + 3145728L)
#define OFF_WP  (OFF_BQ + 3072L)
#define OFF_BP  (OFF_WP + 1048576L)
#define OFF_QN  (OFF_BP + 1024L)
#define OFF_KN  (OFF_QN + 64L)
#define OFF_Q   (OFF_KN + 64L)
#define OFF_K   (OFF_Q  + 4194304L)
#define OFF_V   (OFF_K  + 4194304L)
#define OFF_A   (OFF_V  + 4194304L)

// ---------------------------------------------------------------------------
// dtype detector, vectorized: f32-as-u16 has ~22% exponent fields >= 0x90;
// bf16 N(0,1) has none. 8192 uint4 = 65536 shorts.
// ---------------------------------------------------------------------------
__global__ __launch_bounds__(256) void detect_kernel(
    const unsigned int* __restrict__ xraw, int* __restrict__ flag)
{
    __shared__ int cnt;
    if (threadIdx.x == 0) cnt = 0;
    __syncthreads();
    int local = 0;
    const uint4* x4 = (const uint4*)xraw;
    for (int i = threadIdx.x; i < 8192; i += 256){
        uint4 v = x4[i];
        unsigned int w[4] = {v.x, v.y, v.z, v.w};
        #pragma unroll
        for (int j=0;j<4;j++){
            local += ((w[j] & 0x7F80u) >= 0x4800u);
            local += (((w[j]>>16) & 0x7F80u) >= 0x4800u);
        }
    }
    atomicAdd(&cnt, local);
    __syncthreads();
    if (threadIdx.x == 0) *flag = (cnt > 256) ? 1 : 0;
}

// ---------------------------------------------------------------------------
// canonicalize inputs to bf16, vectorized 4-wide
// ---------------------------------------------------------------------------
__global__ __launch_bounds__(256) void convert_kernel(
    const void* __restrict__ x,  const void* __restrict__ wq,
    const void* __restrict__ bq, const void* __restrict__ wp,
    const void* __restrict__ bp, const void* __restrict__ qn,
    const void* __restrict__ kn, unsigned short* __restrict__ ws,
    const int* __restrict__ flagp)
{
    const int flag = *flagp;
    long i = (long)blockIdx.x*blockDim.x + threadIdx.x;   // 4-elem chunk id
    const long stride = (long)gridDim.x*blockDim.x;
    const long NCH = 2098208L;                            // 8392832/4
    for (; i < NCH; i += stride){
        long j = i; const void* src; long off;
        if (j < 1048576L)                  { src = x;  off = OFF_X;  }
        else if ((j -= 1048576L) < 786432L){ src = wq; off = OFF_WQ; }
        else if ((j -= 786432L)  < 768L)   { src = bq; off = OFF_BQ; }
        else if ((j -= 768L)     < 262144L){ src = wp; off = OFF_WP; }
        else if ((j -= 262144L)  < 256L)   { src = bp; off = OFF_BP; }
        else if ((j -= 256L)     < 16L)    { src = qn; off = OFF_QN; }
        else      { j -= 16L;                src = kn; off = OFF_KN; }
        us4 o;
        if (flag){
            float4 v = ((const float4*)src)[j];
            o.x = f2b(v.x); o.y = f2b(v.y); o.z = f2b(v.z); o.w = f2b(v.w);
        } else {
            o = ((const us4*)src)[j];
        }
        *(us4*)(ws + off + j*4) = o;
    }
}

// ---------------------------------------------------------------------------
// Kernel 1: qkv = x @ Wqkv^T + bqkv, fused per-head RMS norm on q,k.
// m97 structure: 128x128 tile, BK=32, global_load_lds(16B) staging, 2-barrier.
// ---------------------------------------------------------------------------
__global__ __launch_bounds__(256) void qkv_kernel(
    const unsigned short* __restrict__ x,
    const unsigned short* __restrict__ Wqkv,
    const unsigned short* __restrict__ bqkv,
    const unsigned short* __restrict__ qn_w,
    const unsigned short* __restrict__ kn_w,
    unsigned short* __restrict__ qbuf,
    unsigned short* __restrict__ kbuf,
    unsigned short* __restrict__ vbuf)
{
    __shared__ __align__(16) unsigned short tA[128*32];
    __shared__ __align__(16) unsigned short tB[128*32];
    const int tid  = threadIdx.x;
    const int w    = tid >> 6, lane = tid & 63, quad = lane >> 4, c = lane & 15;
    const int m0 = blockIdx.y*128, n0 = blockIdx.x*128;
    const int am = (w>>1)*64, bn = (w&1)*64;

    f32x4 acc[4][4];
    for (int mi=0;mi<4;mi++) for (int ni=0;ni<4;ni++) acc[mi][ni] = {0.f,0.f,0.f,0.f};

    const int i0 = tid, i1 = tid + 256;
    const long ga0 = (long)(m0 + (i0>>2))*D_MODEL + (i0&3)*8;
    const long ga1 = (long)(m0 + (i1>>2))*D_MODEL + (i1&3)*8;
    const long gb0 = (long)(n0 + (i0>>2))*D_MODEL + (i0&3)*8;
    const long gb1 = (long)(n0 + (i1>>2))*D_MODEL + (i1&3)*8;

    for (int k0=0;k0<D_MODEL;k0+=32){
        g2l16(x    + ga0 + k0, tA + i0*8);
        g2l16(x    + ga1 + k0, tA + i1*8);
        g2l16(Wqkv + gb0 + k0, tB + i0*8);
        g2l16(Wqkv + gb1 + k0, tB + i1*8);
        __syncthreads();
        bf16x8 a[4], b[4];
        for (int mi=0;mi<4;mi++) a[mi] = *(const bf16x8*)(tA + (am + mi*16 + c)*32 + quad*8);
        for (int ni=0;ni<4;ni++) b[ni] = *(const bf16x8*)(tB + (bn + ni*16 + c)*32 + quad*8);
        for (int mi=0;mi<4;mi++)
            for (int ni=0;ni<4;ni++)
                acc[mi][ni] = MFMA(a[mi], b[ni], acc[mi][ni]);
        __syncthreads();
    }

    const int nw = n0 + bn, mw = m0 + am;
    const int region = nw >> 10;          // 0=q, 1=k, 2=v
    const int h      = (nw & 1023) >> 6;
    float bias[4], wn[4];
    for (int ni=0;ni<4;ni++){
        bias[ni] = b2f(bqkv[nw + ni*16 + c]);
        wn[ni]   = 1.0f;
    }
    if (region==0) for (int ni=0;ni<4;ni++) wn[ni] = b2f(qn_w[ni*16+c]);
    if (region==1) for (int ni=0;ni<4;ni++) wn[ni] = b2f(kn_w[ni*16+c]);
    unsigned short* dst = (region==0) ? qbuf : (region==1) ? kbuf : vbuf;

    for (int mi=0;mi<4;mi++){
        for (int ni=0;ni<4;ni++)
            for (int r=0;r<4;r++) acc[mi][ni][r] += bias[ni];

        float scale_r[4];
        if (region < 2){
            for (int r=0;r<4;r++){
                float ss = 0.f;
                for (int ni=0;ni<4;ni++){ float v2 = acc[mi][ni][r]; ss += v2*v2; }
                ss += __shfl_xor(ss, 1, 64);
                ss += __shfl_xor(ss, 2, 64);
                ss += __shfl_xor(ss, 4, 64);
                ss += __shfl_xor(ss, 8, 64);
                scale_r[r] = rsqrtf(ss*(1.0f/64.0f) + 1e-6f);
            }
        } else {
            for (int r=0;r<4;r++) scale_r[r] = 1.0f;
        }

        for (int r=0;r<4;r++){
            int m = mw + mi*16 + quad*4 + r;
            int bidx = m >> 11, s = m & 2047;
            long base = ((long)(bidx*NH + h)*SEQ + s)*HD;
            for (int ni=0;ni<4;ni++)
                dst[base + ni*16 + c] = f2b(acc[mi][ni][r] * scale_r[r] * wn[ni]);
        }
    }
}

// ---------------------------------------------------------------------------
// Kernel 2: attention. Fixed-max softmax (|s|<=8 by Cauchy-Schwarz, M=12);
// row-sum via ones-column in V (5th PV n-tile). S^T = K*Q^T operand swap ->
// P stores are ds_write_b64, P reads ds_read_b128 (frag-ordered layout).
// V^T staged by register transpose (8x4B coalesced global + 2 ds_write_b128).
// V and K prefetched one tile ahead; one barrier per tile.
// Block = 4 waves x 32 qrows = 128 qrows, one (b,h). Grid (16, 32).
// ---------------------------------------------------------------------------
__global__ __launch_bounds__(256) void attn_kernel(
    const unsigned short* __restrict__ qbuf,
    const unsigned short* __restrict__ kbuf,
    const unsigned short* __restrict__ vbuf,
    unsigned short* __restrict__ abuf)
{
    const int tid = threadIdx.x, w = tid>>6, lane = tid&63, quad = lane>>4, c = lane&15;
    const int bh = blockIdx.y, qt = blockIdx.x;
    const unsigned short* qb = qbuf + (long)bh*SEQ*HD;
    const unsigned short* kb = kbuf + (long)bh*SEQ*HD;
    const unsigned short* vb = vbuf + (long)bh*SEQ*HD;
    const int qbase = qt*128 + w*32;

    // VT[buf][dim][key], stride 72 (bank-uniform for b128 r/w). dims 64..79:
    // ones-column block for the row-sum trick.
    __shared__ __align__(16) short VT[2][80][72];
    // P frag-ordered: [wave][key8(8)][qrow(32)][j(8)] -> b64 writes, b128 reads
    __shared__ __align__(16) short P[4][2048];
    short* Pw = &P[w][0];

    // init ones-rows of both VT buffers
    for (int i = tid; i < 2*16*72; i += 256){
        int bi = i / 1152, rem = i - bi*1152;
        VT[bi][64 + rem/72][rem%72] = 0;
    }
    __syncthreads();
    if (tid < 128) VT[tid>>6][64][tid&63] = 0x3F80;   // bf16 1.0

    // Q frags (B-operand of S^T): lane holds Q[qbase+mi*16+c][ks*32+quad*8+j]
    bf16x8 aq[2][2];
    for (int mi=0;mi<2;mi++)
        for (int ks=0;ks<2;ks++)
            aq[mi][ks] = *(const bf16x8*)(qb + (long)(qbase + mi*16 + c)*HD + ks*32 + quad*8);

    f32x4 o[2][5];
    for (int mi=0;mi<2;mi++) for (int nt=0;nt<5;nt++) o[mi][nt] = {0.f,0.f,0.f,0.f};

    // V-stage assignment: thread covers dims (d0,d0+1) x keys [kg*8, kg*8+8)
    const int d0 = (tid & 31)*2;
    const int kg = tid >> 5;

    unsigned int vA[8], vB[8];
    bf16x8 kA[4][2], kB[4][2];

    auto stageV = [&](int key0, unsigned int* vr){
        #pragma unroll
        for (int j=0;j<8;j++)
            vr[j] = *(const unsigned int*)(vb + (long)(key0 + kg*8 + j)*HD + d0);
    };
    auto loadK = [&](int key0, bf16x8 (*kf)[2]){
        #pragma unroll
        for (int mt=0;mt<4;mt++)
            #pragma unroll
            for (int ks=0;ks<2;ks++)
                kf[mt][ks] = *(const bf16x8*)(kb + (long)(key0 + mt*16 + c)*HD + ks*32 + quad*8);
    };
    auto writeV = [&](unsigned int* vr, short (*vt)[72]){
        bf16x8 lo, hi;
        #pragma unroll
        for (int j=0;j<8;j++){
            lo[j] = (short)(vr[j] & 0xffffu);
            hi[j] = (short)(vr[j] >> 16);
        }
        *(bf16x8*)(&vt[d0][kg*8])   = lo;
        *(bf16x8*)(&vt[d0+1][kg*8]) = hi;
    };
    auto compute = [&](short (*vt)[72], bf16x8 (*kf)[2]){
        // S^T = K * Q^T : C-layout row = key (quad*4+r), col = qrow (c)
        f32x4 z[4][2];
        #pragma unroll
        for (int mt=0;mt<4;mt++)
            #pragma unroll
            for (int mi=0;mi<2;mi++){
                f32x4 t = {0.f,0.f,0.f,0.f};
                t = MFMA(kf[mt][0], aq[mi][0], t);
                t = MFMA(kf[mt][1], aq[mi][1], t);
                z[mt][mi] = t;
            }
        // p = exp(s-12), s = z/8 -> exp2(z*log2e/8 - 12*log2e); store b64
        #pragma unroll
        for (int mt=0;mt<4;mt++){
            const int key8 = mt*2 + (quad>>1);
            #pragma unroll
            for (int mi=0;mi<2;mi++){
                s4 pk;
                #pragma unroll
                for (int r=0;r<4;r++)
                    pk[r] = (short)f2b(exp2f(z[mt][mi][r]*0.18033688f - 17.312340f));
                *(s4*)(Pw + (key8*32 + mi*16 + c)*8 + (quad&1)*4) = pk;
            }
        }
        // O += P V : A = P frag (b128), B = VT (b128)
        #pragma unroll
        for (int ks=0;ks<2;ks++){
            bf16x8 bv[5];
            #pragma unroll
            for (int nt=0;nt<5;nt++)
                bv[nt] = *(const bf16x8*)(&vt[nt*16 + c][ks*32 + quad*8]);
            #pragma unroll
            for (int mi=0;mi<2;mi++){
                bf16x8 ap = *(const bf16x8*)(Pw + ((ks*4+quad)*32 + mi*16 + c)*8);
                #pragma unroll
                for (int nt=0;nt<5;nt++)
                    o[mi][nt] = MFMA(ap, bv[nt], o[mi][nt]);
            }
        }
    };

    stageV(0, vA); loadK(0, kA);
    for (int tt=0; tt<16; tt++){
        const int t1 = tt*2 + 1;
        writeV(vA, VT[0]);
        __syncthreads();
        stageV(t1*64, vB); loadK(t1*64, kB);
        compute(VT[0], kA);
        writeV(vB, VT[1]);
        __syncthreads();
        if (tt < 15){ stageV((t1+1)*64, vA); loadK((t1+1)*64, kA); }
        compute(VT[1], kB);
    }

    // epilogue: l is column 0 of the nt=4 block (lane c==0 of each quad)
    const int b = bh >> 4, h = bh & 15;
    for (int mi=0;mi<2;mi++)
        for (int r=0;r<4;r++){
            float l = __shfl(o[mi][4][r], (lane & 0x30), 64);
            float inv = 1.0f / l;
            int s = qbase + mi*16 + quad*4 + r;
            long base = ((long)(b*SEQ + s)*NH + h)*HD;
            for (int nt=0;nt<4;nt++)
                abuf[base + nt*16 + c] = f2b(o[mi][nt][r]*inv);
        }
}

// ---------------------------------------------------------------------------
// Kernel 3: out = attn @ Wproj^T + bproj (m97 structure), output dtype by flag
// ---------------------------------------------------------------------------
__global__ __launch_bounds__(256) void proj_kernel(
    const unsigned short* __restrict__ abuf,
    const unsigned short* __restrict__ Wp,
    const unsigned short* __restrict__ bp,
    void* __restrict__ outv,
    const int* __restrict__ flagp)
{
    __shared__ __align__(16) unsigned short tA[128*32];
    __shared__ __align__(16) unsigned short tB[128*32];
    const int tid  = threadIdx.x;
    const int w    = tid >> 6, lane = tid & 63, quad = lane >> 4, c = lane & 15;
    const int m0 = blockIdx.y*128, n0 = blockIdx.x*128;
    const int am = (w>>1)*64, bn = (w&1)*64;
    const int flag = *flagp;

    f32x4 acc[4][4];
    for (int mi=0;mi<4;mi++) for (int ni=0;ni<4;ni++) acc[mi][ni] = {0.f,0.f,0.f,0.f};

    const int i0 = tid, i1 = tid + 256;
    const long ga0 = (long)(m0 + (i0>>2))*D_MODEL + (i0&3)*8;
    const long ga1 = (long)(m0 + (i1>>2))*D_MODEL + (i1&3)*8;
    const long gb0 = (long)(n0 + (i0>>2))*D_MODEL + (i0&3)*8;
    const long gb1 = (long)(n0 + (i1>>2))*D_MODEL + (i1&3)*8;

    for (int k0=0;k0<D_MODEL;k0+=32){
        g2l16(abuf + ga0 + k0, tA + i0*8);
        g2l16(abuf + ga1 + k0, tA + i1*8);
        g2l16(Wp   + gb0 + k0, tB + i0*8);
        g2l16(Wp   + gb1 + k0, tB + i1*8);
        __syncthreads();
        bf16x8 a[4], b[4];
        for (int mi=0;mi<4;mi++) a[mi] = *(const bf16x8*)(tA + (am + mi*16 + c)*32 + quad*8);
        for (int ni=0;ni<4;ni++) b[ni] = *(const bf16x8*)(tB + (bn + ni*16 + c)*32 + quad*8);
        for (int mi=0;mi<4;mi++)
            for (int ni=0;ni<4;ni++)
                acc[mi][ni] = MFMA(a[mi], b[ni], acc[mi][ni]);
        __syncthreads();
    }

    float bias[4];
    for (int ni=0;ni<4;ni++) bias[ni] = b2f(bp[n0 + bn + ni*16 + c]);

    for (int mi=0;mi<4;mi++)
        for (int r=0;r<4;r++){
            long m = m0 + am + mi*16 + quad*4 + r;
            for (int ni=0;ni<4;ni++){
                float val = acc[mi][ni][r] + bias[ni];
                long idx = m*D_MODEL + n0 + bn + ni*16 + c;
                if (flag) ((float*)outv)[idx] = val;
                else      ((unsigned short*)outv)[idx] = f2b(val);
            }
        }
}

extern "C" void kernel_launch(void* const* d_in, const int* in_sizes, int n_in,
                              void* d_out, int out_size, void* d_ws, size_t ws_size,
                              hipStream_t stream)
{
    unsigned short* ws = (unsigned short*)d_ws;
    int* flag = (int*)d_ws;

    hipLaunchKernelGGL(detect_kernel, dim3(1), dim3(256), 0, stream,
                       (const unsigned int*)d_in[0], flag);
    hipLaunchKernelGGL(convert_kernel, dim3(2048), dim3(256), 0, stream,
                       d_in[0], d_in[1], d_in[2], d_in[3], d_in[4], d_in[5], d_in[6],
                       ws, flag);
    hipLaunchKernelGGL(qkv_kernel,  dim3(24,32), dim3(256), 0, stream,
                       ws+OFF_X, ws+OFF_WQ, ws+OFF_BQ, ws+OFF_QN, ws+OFF_KN,
                       ws+OFF_Q, ws+OFF_K, ws+OFF_V);
    hipLaunchKernelGGL(attn_kernel, dim3(16,32), dim3(256), 0, stream,
                       ws+OFF_Q, ws+OFF_K, ws+OFF_V, ws+OFF_A);
    hipLaunchKernelGGL(proj_kernel, dim3(8,32),  dim3(256), 0, stream,
                       ws+OFF_A, ws+OFF_WP, ws+OFF_BP, d_out, flag);
}